// Round 19
// baseline (164.045 us; speedup 1.0000x reference)
//
#include <hip/hip_runtime.h>
#include <stdint.h>

// Problem constants
#define QKV_N 6144
#define ATT_SCALE 0.08838834764831845f   // 1/sqrt(128)

typedef __attribute__((ext_vector_type(8))) short short8;   // 8 bf16 (4 VGPRs)
typedef __attribute__((ext_vector_type(4))) float f32x4;

__device__ __forceinline__ uint16_t f2b(float x){
  uint32_t u = __float_as_uint(x);
  uint32_t r = (u + 0x7fffu + ((u >> 16) & 1u)) >> 16;   // RNE
  return (uint16_t)r;
}
__device__ __forceinline__ float b2f(uint16_t h){
  return __uint_as_float(((uint32_t)h) << 16);
}
__device__ __forceinline__ void g2l16(const void* g, void* l){
  __builtin_amdgcn_global_load_lds((const __attribute__((address_space(1))) void*)g,
                                   (__attribute__((address_space(3))) void*)l, 16, 0, 0);
}

// ---------------- fused prep: fp32->bf16 converts + RoPE tables ----------------
__device__ __forceinline__ void cvt8(const float* __restrict__ in, uint16_t* __restrict__ out, int i){
  const float4* p = (const float4*)in;
  float4 a = p[2*i], b = p[2*i+1];
  union { short8 v; uint16_t u[8]; } o;
  o.u[0]=f2b(a.x); o.u[1]=f2b(a.y); o.u[2]=f2b(a.z); o.u[3]=f2b(a.w);
  o.u[4]=f2b(b.x); o.u[5]=f2b(b.y); o.u[6]=f2b(b.z); o.u[7]=f2b(b.w);
  ((short8*)out)[i] = o.v;
}

__global__ __launch_bounds__(256) void k_prep(const float* __restrict__ x,
                                              const float* __restrict__ wqkv,
                                              const float* __restrict__ wo,
                                              uint16_t* __restrict__ xb,
                                              uint16_t* __restrict__ wqkvb,
                                              uint16_t* __restrict__ wob,
                                              float* __restrict__ ct,
                                              float* __restrict__ st){
  const int b = blockIdx.x, tid = threadIdx.x;
  if (b < 2048) {                         // x: 4.19M elems
    cvt8(x, xb, b*256 + tid);
  } else if (b < 8192) {                  // Wqkv: 12.58M elems
    cvt8(wqkv, wqkvb, (b - 2048)*256 + tid);
  } else if (b < 10240) {                 // Wo: 4.19M elems
    cvt8(wo, wob, (b - 8192)*256 + tid);
  } else {                                // tables [2048][32]
    int i = (b - 10240)*256 + tid;
    int s = i >> 5, d = i & 31;
    float inv = __expf(-(float)d * (9.210340371976184f / 32.0f));
    float f = (float)s * inv;
    ct[i] = cosf(f);
    st[i] = sinf(f);
  }
}

// ---------------- gemmA v4: 128x192 tile, BK=64, SINGLE 40KB buffer, stage-after-read ----------------
// qkv = x @ Wqkv^T + bias, bf16 out. M=2048 N=6144 K=2048. Grid 512.
// 8 waves (2Mx4N), per-wave 64x48, 24 MFMA between barrier pairs.
// v3 lesson: BK=64 (1 barrier per 24 MFMA) beat r11 even at 1 block/CU; but
// 2x80KB missed 2-blocks/CU. v4 keeps BK=64 AND restores 2 blocks/CU:
// all fragment reads land in registers at loop top, so the double buffer is
// unneeded -- reads; __syncthreads (#1: all reads done; implicit vmcnt drain
// free, nothing outstanding); stage t+1 into the SAME buffer; 24 MFMA from
// regs; __syncthreads (#2: implicit vmcnt(0) drains staging; all writes
// visible). Write-after-read is unconditional (no stage write can issue
// before barrier #1). LDS 40KB -> 2 blocks/CU with slack.
// Per-row swizzle slot^=row&7 (r11-verified conflict-free class).
__global__ __launch_bounds__(512, 4) void k_gemmA(const uint16_t* __restrict__ A,
                                                  const uint16_t* __restrict__ B,
                                                  const float* __restrict__ bias,
                                                  uint16_t* __restrict__ C){
  __shared__ uint16_t Ls[20480];   // [A 8192 | B 12288] elems = 40 KB
  const int K = 2048, N = 6144;

  const int wg = blockIdx.x;                   // 512 blocks
  const int xcd = wg & 7, bi = wg >> 3;        // bi in [0,64)
  const int m0 = (xcd*2 + (bi & 1)) * 128;     // XCD x: m-panels {2x, 2x+1}
  const int n0 = (bi >> 1) * 192;              // 32 n-panels

  const int tid = threadIdx.x;
  const int wid = tid >> 6, l = tid & 63;
  const int wm = wid >> 2, wn = wid & 3;       // 2 x 4 wave grid
  const int g = l >> 4, c = l & 15;

  // staging: A rows 0-127 (2 loads/thr), B rows 0-191 (3 loads/thr); 16B loads.
  // LDS dst linear (f*8 elems); source col pre-swizzled (q ^ (row&7)).
  size_t srcA[2]; int dstA[2];
  #pragma unroll
  for (int j = 0; j < 2; ++j) {
    int f = tid + 512*j, r = f >> 3, q = f & 7;
    srcA[j] = (size_t)(m0 + r) * K + ((q ^ (r & 7)) << 3);
    dstA[j] = f * 8;
  }
  size_t srcB[3]; int dstB[3];
  #pragma unroll
  for (int j = 0; j < 3; ++j) {
    int f = tid + 512*j, r = f >> 3, q = f & 7;
    srcB[j] = (size_t)(n0 + r) * K + ((q ^ (r & 7)) << 3);
    dstB[j] = 8192 + f * 8;
  }

  // read-side: row = base + c (base mult of 16); slot = (kk*4+g) ^ (c&7)
  const int sl0 = ((g)     ^ (c & 7)) << 3;    // kk=0 slot byte offset (elems)
  const int sl1 = ((4 | g) ^ (c & 7)) << 3;    // kk=1
  const int arow = (wm*64 + c) * 64;           // A row base addr (elems)
  const int brow = 8192 + (wn*48 + c) * 64;    // B region

  f32x4 acc[4][3] = {};
  const int NT = K >> 6;                       // 32 tiles of BK=64

  // prologue: stage tile 0
  #pragma unroll
  for (int j = 0; j < 2; ++j) g2l16(A + srcA[j], (void*)(Ls + dstA[j]));
  #pragma unroll
  for (int j = 0; j < 3; ++j) g2l16(B + srcB[j], (void*)(Ls + dstB[j]));
  __syncthreads();   // implicit vmcnt(0)+lgkmcnt(0): tile 0 resident

  #pragma unroll 2
  for (int t = 0; t < NT; ++t) {
    // fragment reads (both k-halves) into registers
    short8 a[4][2], b[3][2];
    #pragma unroll
    for (int mi = 0; mi < 4; ++mi) {
      a[mi][0] = *(const short8*)&Ls[arow + mi*1024 + sl0];
      a[mi][1] = *(const short8*)&Ls[arow + mi*1024 + sl1];
    }
    #pragma unroll
    for (int ni = 0; ni < 3; ++ni) {
      b[ni][0] = *(const short8*)&Ls[brow + ni*1024 + sl0];
      b[ni][1] = *(const short8*)&Ls[brow + ni*1024 + sl1];
    }
    __syncthreads();   // #1: all waves' reads complete (lgkmcnt drained per wave)

    // stage next tile into the SAME buffer (cannot beat any read: issued
    // strictly after barrier #1)
    if (t + 1 < NT) {
      const size_t ko = (size_t)(t + 1) * 64;
      #pragma unroll
      for (int j = 0; j < 2; ++j) g2l16(A + srcA[j] + ko, (void*)(Ls + dstA[j]));
      #pragma unroll
      for (int j = 0; j < 3; ++j) g2l16(B + srcB[j] + ko, (void*)(Ls + dstB[j]));
    }

    __builtin_amdgcn_s_setprio(1);
    #pragma unroll
    for (int mi = 0; mi < 4; ++mi)
      #pragma unroll
      for (int ni = 0; ni < 3; ++ni)
        #pragma unroll
        for (int kk = 0; kk < 2; ++kk)
          acc[mi][ni] = __builtin_amdgcn_mfma_f32_16x16x32_bf16(a[mi][kk], b[ni][kk], acc[mi][ni], 0, 0, 0);
    __builtin_amdgcn_s_setprio(0);

    __syncthreads();   // #2: implicit vmcnt(0) drains staging; tile t+1 visible
  }

  // epilogue: bias + bf16 store (identical mapping to r11)
  #pragma unroll
  for (int ni = 0; ni < 3; ++ni) {
    const int col = n0 + wn*48 + ni*16 + c;
    const float bvl = bias[col];
    #pragma unroll
    for (int mi = 0; mi < 4; ++mi) {
      const int row0 = m0 + wm*64 + mi*16 + g*4;
      #pragma unroll
      for (int j = 0; j < 4; ++j)
        C[(size_t)(row0 + j)*N + col] = f2b(acc[mi][ni][j] + bvl);
    }
  }
}

// ---------------- 128x128 GEMM, BK=32, 4-buffer counted-vmcnt, f32 out (r9 proven) ----------------
__global__ __launch_bounds__(512, 1) void k_gemm128(const uint16_t* __restrict__ A,
                                                    const uint16_t* __restrict__ B,
                                                    const float* __restrict__ bias,
                                                    float* __restrict__ C,
                                                    int M, int N, int K){
  __shared__ uint16_t As[4*4096];   // [buf][rp(64)][slot8][8]
  __shared__ uint16_t Bs[4*4096];

  const int wg = blockIdx.x;
  const int xcd = wg & 7, bi = wg >> 3;
  const int m0 = (xcd*2 + (bi & 1)) * 128;     // XCD x: m-panels {2x, 2x+1}
  const int n0 = (bi >> 1) * 128;              // all 16 n-panels per XCD

  const int tid = threadIdx.x;
  const int wid = tid >> 6, l = tid & 63;
  const int wm = wid >> 2, wn = wid & 3;
  const int g = l >> 4, c = l & 15;

  const int rp_s = tid >> 3, q_s = tid & 7, s_s = q_s ^ (rp_s & 7);
  const int srcA = (m0 + rp_s*2 + (s_s >> 2)) * K + (s_s & 3) * 8;
  const int srcB = (n0 + rp_s*2 + (s_s >> 2)) * K + (s_s & 3) * 8;

  const int pg  = ((c & 1) << 2) | g;
  const int slb = (pg ^ ((c >> 1) & 7)) << 3;
  const int ra0 = wm*32 + (c >> 1);            // rows wm*64+c
  const int rb0 = wn*16 + (c >> 1);            // rows wn*32+c

  f32x4 acc[4][2] = {};
  const int NT = K >> 5;

  #pragma unroll
  for (int t0 = 0; t0 < 3; ++t0) {
    g2l16(A + srcA + t0*32, (void*)(As + t0*4096 + tid*8));
    g2l16(B + srcB + t0*32, (void*)(Bs + t0*4096 + tid*8));
  }
  asm volatile("s_waitcnt vmcnt(4)" ::: "memory");
  __builtin_amdgcn_s_barrier();

  #pragma unroll 4
  for (int t = 0; t < NT; ++t) {
    const uint16_t* __restrict__ Ab = As + (t & 3)*4096;
    const uint16_t* __restrict__ Bb = Bs + (t & 3)*4096;
    const int t3 = t + 3;
    const int b3 = (t3 & 3)*4096;

    short8 av[4], bv[2];
    #pragma unroll
    for (int mi = 0; mi < 4; ++mi)
      av[mi] = *(const short8*)&Ab[(ra0 + mi*8)*64 + slb];
    #pragma unroll
    for (int ni = 0; ni < 2; ++ni)
      bv[ni] = *(const short8*)&Bb[(rb0 + ni*8)*64 + slb];
    if (t3 < NT) {
      g2l16(A + srcA + t3*32, (void*)(As + b3 + tid*8));
      g2l16(B + srcB + t3*32, (void*)(Bs + b3 + tid*8));
    }
    __builtin_amdgcn_s_barrier();
    __builtin_amdgcn_s_setprio(1);
    #pragma unroll
    for (int mi = 0; mi < 4; ++mi)
      #pragma unroll
      for (int ni = 0; ni < 2; ++ni)
        acc[mi][ni] = __builtin_amdgcn_mfma_f32_16x16x32_bf16(av[mi], bv[ni], acc[mi][ni], 0, 0, 0);
    __builtin_amdgcn_s_setprio(0);
    asm volatile("s_waitcnt vmcnt(4)" ::: "memory");
    __builtin_amdgcn_s_barrier();
  }

  #pragma unroll
  for (int ni = 0; ni < 2; ++ni) {
    const int col = n0 + wn*32 + ni*16 + c;
    const float bvl = bias[col];
    #pragma unroll
    for (int mi = 0; mi < 4; ++mi) {
      const int row0 = m0 + wm*64 + mi*16 + g*4;
      #pragma unroll
      for (int j = 0; j < 4; ++j)
        C[(size_t)(row0 + j)*N + col] = acc[mi][ni][j] + bvl;
    }
  }
}

// ---------------- fused RoPE head-split (Q,K) + V transpose ----------------
__global__ __launch_bounds__(256) void k_rope_vt(const uint16_t* __restrict__ qkv,
                                                 const float* __restrict__ ct,
                                                 const float* __restrict__ st,
                                                 uint16_t* __restrict__ qo,
                                                 uint16_t* __restrict__ ko,
                                                 uint16_t* __restrict__ vt){
  const int blk = blockIdx.x, tid = threadIdx.x;
  if (blk < 4096) {
    int idx = blk * 256 + tid;   // which(2) x h(16) x s(2048) x db(16)
    int db = idx & 15;
    int s  = (idx >> 4) & 2047;
    int h  = (idx >> 15) & 15;
    int which = idx >> 19;
    const uint16_t* src = qkv + (size_t)s * QKV_N + which * 2048 + h * 128;
    uint16_t* dst = (which ? ko : qo) + (((size_t)(h*2048 + s)) << 7) + db*8;
    const float scale = which ? 1.0f : ATT_SCALE;
    int d0 = db * 8;
    union { short8 v; uint16_t u[8]; } o;
    if (d0 >= 64) {
      short8 xv = *(const short8*)(src + d0);
      #pragma unroll
      for (int e = 0; e < 8; ++e) o.u[e] = f2b(b2f((uint16_t)xv[e]) * scale);
    } else {
      int dd = d0 & 31;
      short8 a = *(const short8*)(src + dd);
      short8 b = *(const short8*)(src + dd + 32);
      float4 c0 = *(const float4*)(ct + s*32 + dd);
      float4 c1 = *(const float4*)(ct + s*32 + dd + 4);
      float4 s0 = *(const float4*)(st + s*32 + dd);
      float4 s1 = *(const float4*)(st + s*32 + dd + 4);
      float cc[8] = {c0.x,c0.y,c0.z,c0.w,c1.x,c1.y,c1.z,c1.w};
      float ss[8] = {s0.x,s0.y,s0.z,s0.w,s1.x,s1.y,s1.z,s1.w};
      #pragma unroll
      for (int e = 0; e < 8; ++e) {
        float x1 = b2f((uint16_t)a[e]), x2 = b2f((uint16_t)b[e]);
        float v = (d0 < 32) ? (x1*cc[e] - x2*ss[e]) : (x1*ss[e] + x2*cc[e]);
        o.u[e] = f2b(v * scale);
      }
    }
    *(short8*)dst = o.v;
  } else {
    __shared__ uint16_t tl[64][80];
    const int b = blk - 4096;               // h(16) x dt(2) x st(32)
    const int st_ = b & 31, dt = (b >> 5) & 1, h = b >> 6;
    const int s_l = tid >> 2, cch = (tid & 3) * 16;
    const uint16_t* src = qkv + (size_t)(st_*64 + s_l) * QKV_N + 4096 + h*128 + dt*64 + cch;
    short8 a = *(const short8*)src;
    short8 b2 = *(const short8*)(src + 8);
    #pragma unroll
    for (int e = 0; e < 8; ++e) {
      tl[cch + e][s_l]     = (uint16_t)a[e];
      tl[cch + 8 + e][s_l] = (uint16_t)b2[e];
    }
    __syncthreads();
    const int d_l = tid >> 2;
    uint16_t* dst = vt + ((size_t)h << 18) + (size_t)(dt*64 + d_l) * 2048 + st_*64 + cch;
    *(short8*)dst       = *(const short8*)&tl[d_l][cch];
    *(short8*)(dst + 8) = *(const short8*)&tl[d_l][cch + 8];
  }
}

// ---------------- causal flash attention v5 (r12 proven) ----------------
__global__ __launch_bounds__(512, 1) void k_attn(const uint16_t* __restrict__ Q,
                                                 const uint16_t* __restrict__ Kb,
                                                 const uint16_t* __restrict__ Vtg,
                                                 uint16_t* __restrict__ Out){
  __shared__ uint16_t Ks[2][2][64*128];   // [group][buf][k][d], swizzled
  __shared__ uint16_t Vs[2][2][128*64];   // [group][buf][d][k], swizzled
  __shared__ uint16_t Ps[8][16*88];       // per-wave P [q][k], stride 88

  const int bid = blockIdx.x;             // 256 blocks
  const int lin = (bid & 7) * 32 + (bid >> 3);
  const int h = lin >> 4;                 // XCD x gets heads {2x, 2x+1}
  const int pair = lin & 15;              // fold-pair within head

  const int tid = threadIdx.x, w = tid >> 6, l = tid & 63;
  const int gid = w >> 2, wq = w & 3;     // group, wave-in-group
  const int tg = tid & 255;               // thread index within group
  const int g = l >> 4, c = l & 15;
  const int swz = (c & 7) << 4;           // read-side byte swizzle

  const uint16_t* __restrict__ Qh = Q   + ((size_t)h << 18);
  const uint16_t* __restrict__ Kh = Kb  + ((size_t)h << 18);
  const uint16_t* __restrict__ Vh = Vtg + ((size_t)h << 18);
  float* scratch = (float*)&Ks[0][0][0];  // merge scratch (safe after last barrier)

  int koff[4], voff[4];
  #pragma unroll
  for (int j = 0; j < 4; ++j) {
    int kr = j*16 + (tg >> 4);                           // K row in tile
    koff[j] = kr*128 + (((tg & 15) ^ (kr & 7)) << 3);
    int vd = j*32 + (tg >> 3);                           // V^T row (d)
    voff[j] = vd*2048 + (((tg & 7) ^ (vd & 7)) << 3);
  }

  uint16_t* KsG = &Ks[gid][0][0];   // my group's K buffers (2 x 8192 elems)
  uint16_t* VsG = &Vs[gid][0][0];

  #pragma unroll 1
  for (int half = 0; half < 2; ++half) {
    const int qt = half ? (31 - pair) : pair;   // 64-row q-tile index
    const int nt = qt + 1;                      // KV tiles (KVBLK=64)
    const int nsteps = (nt + 1) >> 1;
    const int qrow = qt*64 + wq*16 + c;

    short8 qf[4];
    #pragma unroll
    for (int t = 0; t < 4; ++t)
      qf[t] = *(const short8*)&Qh[(size_t)qrow*128 + t*32 + g*8];

    f32x4 acc[8] = {};
    float mrow[4], lsum[4];
    #pragma unroll
    for (int j = 0; j < 4; ++j) { mrow[j] = -3e38f; lsum[j] = 0.0f; }

    if (gid < nt) {
      #pragma unroll
      for (int j = 0; j < 4; ++j) {
        g2l16(Kh + (size_t)gid*8192 + koff[j], (void*)(KsG + j*2048 + tg*8));
        g2l16(Vh + gid*64 + voff[j],           (void*)(VsG + j*2048 + tg*8));
      }
    }
    asm volatile("s_waitcnt vmcnt(0)" ::: "memory");
    __syncthreads();

    #pragma unroll 1
    for (int step = 0; step < nsteps; ++step) {
      const int kt = 2*step + gid;
      const int cur = step & 1;
      if (kt + 2 < nt) {
        const int k1 = kt + 2;
        #pragma unroll
        for (int j = 0; j < 4; ++j) {
          g2l16(Kh + (size_t)k1*8192 + koff[j], (void*)(KsG + (cur^1)*8192 + j*2048 + tg*8));
          g2l16(Vh + k1*64 + voff[j],           (void*)(VsG + (cur^1)*8192 + j*2048 + tg*8));
        }
      }

      if (kt < nt) {
        const int k0 = kt * 64;
        const uint16_t* Kcur = KsG + cur*8192;
        const uint16_t* Vcur = VsG + cur*8192;

        f32x4 sc4[4] = {};
        __builtin_amdgcn_s_setprio(1);
        #pragma unroll
        for (int ct2 = 0; ct2 < 4; ++ct2) {
          const char* krp = (const char*)Kcur + (ct2*16 + c)*256;
          #pragma unroll
          for (int t = 0; t < 4; ++t) {
            short8 kb = *(const short8*)(krp + ((t*64 + g*16) ^ swz));
            sc4[ct2] = __builtin_amdgcn_mfma_f32_16x16x32_bf16(qf[t], kb, sc4[ct2], 0, 0, 0);
          }
        }
        __builtin_amdgcn_s_setprio(0);

        // online softmax: defer-max fast path + per-lane partial l
        const bool lastt = (kt == nt - 1);
        float va[4][4];
        float m4[4];
        int fastok = 1;
        #pragma unroll
        for (int j = 0; j < 4; ++j) {
          const int qg = qt*64 + wq*16 + g*4 + j;
          float v0 = sc4[0][j], v1 = sc4[1][j], v2 = sc4[2][j], v3 = sc4[3][j];
          if (lastt) {
            if (k0 +      c > qg) v0 = -3e38f;
            if (k0 + 16 + c > qg) v1 = -3e38f;
            if (k0 + 32 + c > qg) v2 = -3e38f;
            if (k0 + 48 + c > qg) v3 = -3e38f;
          }
          va[j][0] = v0; va[j][1] = v1; va[j][2] = v2; va[j][3] = v3;
          float m = fmaxf(fmaxf(fmaxf(v0, v1), v2), v3);
          m4[j] = m;
          fastok &= (m <= mrow[j] + 8.0f) ? 1 : 0;
        }
        if (__all(fastok)) {
          #pragma unroll
          for (int j = 0; j < 4; ++j) {
            const float mj = mrow[j];
            const float p0 = __expf(va[j][0] - mj), p1 = __expf(va[j][1] - mj),
                        p2 = __expf(va[j][2] - mj), p3 = __expf(va[j][3] - mj);
            lsum[j] += (p0 + p1) + (p2 + p3);
            uint16_t* pw = &Ps[w][(g*4 + j)*88];
            pw[c] = f2b(p0); pw[16+c] = f2b(p1); pw[32+c] = f2b(p2); pw[48+c] = f2b(p3);
          }
        } else {
          #pragma unroll
          for (int j = 0; j < 4; ++j) {
            float t0 = m4[j];
            #pragma unroll
            for (int d2 = 1; d2 < 16; d2 <<= 1) t0 = fmaxf(t0, __shfl_xor(t0, d2, 64));
            const float mn = fmaxf(mrow[j], t0);
            const float scl = __expf(mrow[j] - mn);
            const float p0 = __expf(va[j][0] - mn), p1 = __expf(va[j][1] - mn),
                        p2 = __expf(va[j][2] - mn), p3 = __expf(va[j][3] - mn);
            lsum[j] = lsum[j]*scl + (p0 + p1) + (p2 + p3);
            mrow[j] = mn;
            #pragma unroll
            for (int n = 0; n < 8; ++n) acc[n][j] *= scl;
            uint16_t* pw = &Ps[w][(g*4 + j)*88];
            pw[c] = f2b(p0); pw[16+c] = f2b(p1); pw[32+c] = f2b(p2); pw[48+c] = f2b(p3);
          }
        }

        __builtin_amdgcn_s_setprio(1);
        #pragma unroll
        for (int kk = 0; kk < 2; ++kk) {
          short8 pf = *(const short8*)&Ps[w][c*88 + kk*32 + g*8];
          #pragma unroll
          for (int n = 0; n < 8; ++n) {
            const char* vrp = (const char*)Vcur + (n*16 + c)*128;
            short8 vf = *(const short8*)(vrp + ((kk*64 + g*16) ^ swz));
            acc[n] = __builtin_amdgcn_mfma_f32_16x16x32_bf16(pf, vf, acc[n], 0, 0, 0);
          }
        }
        __builtin_amdgcn_s_setprio(0);
      }

      asm volatile("s_waitcnt vmcnt(0)" ::: "memory");
      __syncthreads();
    }

    // reduce per-lane l partials -> per-row l (once per q-tile)
    float lrow[4];
    #pragma unroll
    for (int j = 0; j < 4; ++j) {
      float rs = lsum[j];
      #pragma unroll
      for (int d2 = 1; d2 < 16; d2 <<= 1) rs += __shfl_xor(rs, d2, 64);
      lrow[j] = rs;
    }

    // ---- merge group partial states: B (gid=1) publishes, A (gid=0) combines ----
    float* Up = scratch + wq * 2112;      // U[16][128] + m[16] + l[16]
    if (gid == 1) {
      #pragma unroll
      for (int j = 0; j < 4; ++j) {
        const int row = g*4 + j;
        #pragma unroll
        for (int n = 0; n < 8; ++n)
          Up[row*128 + n*16 + c] = acc[n][j];
        if (c == 0) { Up[2048 + row] = mrow[j]; Up[2064 + row] = lrow[j]; }
      }
    }
    __syncthreads();
    if (gid == 0) {
      #pragma unroll
      for (int j = 0; j < 4; ++j) {
        const int row = g*4 + j;
        const int qg = qt*64 + wq*16 + row;
        const float mB = Up[2048 + row], lB = Up[2064 + row];
        const float mn = fmaxf(mrow[j], mB);
        const float e1 = __expf(mrow[j] - mn);
        const float e2 = __expf(mB - mn);
        const float inv = 1.0f / (lrow[j]*e1 + lB*e2);
        #pragma unroll
        for (int n = 0; n < 8; ++n) {
          const float u = acc[n][j]*e1 + Up[row*128 + n*16 + c]*e2;
          Out[(size_t)qg*2048 + h*128 + n*16 + c] = f2b(u * inv);
        }
      }
    }
    __syncthreads();   // protect scratch before next half's staging overwrites K bufs
  }
}

extern "C" void kernel_launch(void* const* d_in, const int* in_sizes, int n_in,
                              void* d_out, int out_size, void* d_ws, size_t ws_size,
                              hipStream_t stream){
  const float* x    = (const float*)d_in[0];
  const float* Wqkv = (const float*)d_in[1];
  const float* bqkv = (const float*)d_in[2];
  const float* Wo   = (const float*)d_in[3];
  const float* bo   = (const float*)d_in[4];

  char* ws = (char*)d_ws;
  uint16_t* q_bf    = (uint16_t*)(ws);                 //  8.39 MB [16][2048][128]
  uint16_t* k_bf    = (uint16_t*)(ws + 8388608);       //  8.39 MB [16][2048][128]
  uint16_t* vt_bf   = (uint16_t*)(ws + 16777216);      //  8.39 MB [16][128][2048]
  uint16_t* attn_bf = (uint16_t*)(ws + 25165824);      //  8.39 MB (aliased with x_bf)
  uint16_t* x_bf    = attn_bf;                         //  x dead before attn writes
  uint16_t* wqkv_bf = (uint16_t*)(ws + 33554432);      // 25.17 MB
  uint16_t* wo_bf   = (uint16_t*)(ws + 58720256);      //  8.39 MB
  uint16_t* qkv_bf  = (uint16_t*)(ws + 67108864);      // 25.17 MB
  float*    cos_t   = (float*)(ws + 92274688);         //  0.26 MB
  float*    sin_t   = (float*)(ws + 92536832);         //  0.26 MB

  // fused converts + tables
  k_prep<<<dim3(10496), dim3(256), 0, stream>>>(x, Wqkv, Wo, x_bf, wqkv_bf, wo_bf,
                                                cos_t, sin_t);
  // qkv = x @ Wqkv^T + b   -> bf16 [2048][6144]  (BK=64, single 40KB buf, 512 blocks, 2/CU)
  k_gemmA<<<dim3(512), dim3(512), 0, stream>>>(x_bf, wqkv_bf, bqkv, qkv_bf);
  // RoPE + split Q,K (Q pre-scaled) + V transpose to [h][d][s]
  k_rope_vt<<<dim3(5120), dim3(256), 0, stream>>>(qkv_bf, cos_t, sin_t, q_bf, k_bf, vt_bf);
  // causal flash attention -> attn_bf [2048][2048]
  k_attn<<<dim3(256), dim3(512), 0, stream>>>(q_bf, k_bf, vt_bf, attn_bf);
  // out = attn @ Wo^T + bo -> f32 d_out (128^2 4-buffer pipeline, 256 blocks)
  k_gemm128<<<dim3(256), dim3(512), 0, stream>>>(attn_bf, wo_bf, bo, (float*)d_out,
                                                 2048, 2048, 2048);
}

// Round 20
// 161.488 us; speedup vs baseline: 1.0158x; 1.0158x over previous
//
#include <hip/hip_runtime.h>
#include <stdint.h>

// Problem constants
#define QKV_N 6144
#define ATT_SCALE 0.08838834764831845f   // 1/sqrt(128)

typedef __attribute__((ext_vector_type(8))) short short8;   // 8 bf16 (4 VGPRs)
typedef __attribute__((ext_vector_type(4))) float f32x4;

__device__ __forceinline__ uint16_t f2b(float x){
  uint32_t u = __float_as_uint(x);
  uint32_t r = (u + 0x7fffu + ((u >> 16) & 1u)) >> 16;   // RNE
  return (uint16_t)r;
}
__device__ __forceinline__ float b2f(uint16_t h){
  return __uint_as_float(((uint32_t)h) << 16);
}
__device__ __forceinline__ void g2l16(const void* g, void* l){
  __builtin_amdgcn_global_load_lds((const __attribute__((address_space(1))) void*)g,
                                   (__attribute__((address_space(3))) void*)l, 16, 0, 0);
}

// ---------------- fused prep: fp32->bf16 converts + RoPE tables ----------------
__device__ __forceinline__ void cvt8(const float* __restrict__ in, uint16_t* __restrict__ out, int i){
  const float4* p = (const float4*)in;
  float4 a = p[2*i], b = p[2*i+1];
  union { short8 v; uint16_t u[8]; } o;
  o.u[0]=f2b(a.x); o.u[1]=f2b(a.y); o.u[2]=f2b(a.z); o.u[3]=f2b(a.w);
  o.u[4]=f2b(b.x); o.u[5]=f2b(b.y); o.u[6]=f2b(b.z); o.u[7]=f2b(b.w);
  ((short8*)out)[i] = o.v;
}

__global__ __launch_bounds__(256) void k_prep(const float* __restrict__ x,
                                              const float* __restrict__ wqkv,
                                              const float* __restrict__ wo,
                                              uint16_t* __restrict__ xb,
                                              uint16_t* __restrict__ wqkvb,
                                              uint16_t* __restrict__ wob,
                                              float* __restrict__ ct,
                                              float* __restrict__ st){
  const int b = blockIdx.x, tid = threadIdx.x;
  if (b < 2048) {                         // x: 4.19M elems
    cvt8(x, xb, b*256 + tid);
  } else if (b < 8192) {                  // Wqkv: 12.58M elems
    cvt8(wqkv, wqkvb, (b - 2048)*256 + tid);
  } else if (b < 10240) {                 // Wo: 4.19M elems
    cvt8(wo, wob, (b - 8192)*256 + tid);
  } else {                                // tables [2048][32]
    int i = (b - 10240)*256 + tid;
    int s = i >> 5, d = i & 31;
    float inv = __expf(-(float)d * (9.210340371976184f / 32.0f));
    float f = (float)s * inv;
    ct[i] = cosf(f);
    st[i] = sinf(f);
  }
}

// ---------------- gemmA v3: 128x192 tile, BK=64, 2-buffer (80 KB), 1 barrier/tile ----------------
// (r18 proven best: 60.6 us) 8 waves (2Mx4N), per-wave 64x48, 24 MFMA between
// barriers. BK=64 halves barriers/FLOP vs r11; staging for t+1 issues during
// tile t's compute into the other buffer and has a full tile to land.
// v4 lesson: single-buffer stage-after-read (2 barriers + compressed staging
// window) loses even at 2 blocks/CU -- barrier/window structure > TLP here.
__global__ __launch_bounds__(512, 1) void k_gemmA(const uint16_t* __restrict__ A,
                                                  const uint16_t* __restrict__ B,
                                                  const float* __restrict__ bias,
                                                  uint16_t* __restrict__ C){
  __shared__ uint16_t Ls[2*20480];   // [buf][A 8192 | B 12288] elems = 80 KB
  const int K = 2048, N = 6144;

  const int wg = blockIdx.x;                   // 512 blocks
  const int xcd = wg & 7, bi = wg >> 3;        // bi in [0,64)
  const int m0 = (xcd*2 + (bi & 1)) * 128;     // XCD x: m-panels {2x, 2x+1}
  const int n0 = (bi >> 1) * 192;              // 32 n-panels

  const int tid = threadIdx.x;
  const int wid = tid >> 6, l = tid & 63;
  const int wm = wid >> 2, wn = wid & 3;       // 2 x 4 wave grid
  const int g = l >> 4, c = l & 15;

  // staging: A rows 0-127 (2 loads/thr), B rows 0-191 (3 loads/thr); 16B loads.
  // LDS dst is linear (f*8 elems); source col pre-swizzled (q ^ (row&7)).
  size_t srcA[2]; int dstA[2];
  #pragma unroll
  for (int j = 0; j < 2; ++j) {
    int f = tid + 512*j, r = f >> 3, q = f & 7;
    srcA[j] = (size_t)(m0 + r) * K + ((q ^ (r & 7)) << 3);
    dstA[j] = f * 8;
  }
  size_t srcB[3]; int dstB[3];
  #pragma unroll
  for (int j = 0; j < 3; ++j) {
    int f = tid + 512*j, r = f >> 3, q = f & 7;
    srcB[j] = (size_t)(n0 + r) * K + ((q ^ (r & 7)) << 3);
    dstB[j] = 8192 + f * 8;
  }

  // read-side: row = base + c (base mult of 16); slot = (kk*4+g) ^ (c&7)
  const int sl0 = ((g)     ^ (c & 7)) << 3;    // kk=0 slot byte offset (elems)
  const int sl1 = ((4 | g) ^ (c & 7)) << 3;    // kk=1
  const int arow = (wm*64 + c) * 64;           // A row base addr (elems)
  const int brow = 8192 + (wn*48 + c) * 64;    // B region

  f32x4 acc[4][3] = {};
  const int NT = K >> 6;                       // 32 tiles of BK=64

  // prologue: stage tile 0 -> buf 0
  #pragma unroll
  for (int j = 0; j < 2; ++j) g2l16(A + srcA[j], (void*)(Ls + dstA[j]));
  #pragma unroll
  for (int j = 0; j < 3; ++j) g2l16(B + srcB[j], (void*)(Ls + dstB[j]));
  asm volatile("s_waitcnt vmcnt(0)" ::: "memory");
  __builtin_amdgcn_s_barrier();

  #pragma unroll 2
  for (int t = 0; t < NT; ++t) {
    const uint16_t* __restrict__ Lb = Ls + (t & 1)*20480;
    uint16_t* __restrict__ Ln = Ls + ((t + 1) & 1)*20480;

    // fragment reads (both k-halves)
    short8 a[4][2], b[3][2];
    #pragma unroll
    for (int mi = 0; mi < 4; ++mi) {
      a[mi][0] = *(const short8*)&Lb[arow + mi*1024 + sl0];
      a[mi][1] = *(const short8*)&Lb[arow + mi*1024 + sl1];
    }
    #pragma unroll
    for (int ni = 0; ni < 3; ++ni) {
      b[ni][0] = *(const short8*)&Lb[brow + ni*1024 + sl0];
      b[ni][1] = *(const short8*)&Lb[brow + ni*1024 + sl1];
    }

    // issue next tile's stage into the other buffer (safe: its readers
    // finished before the previous barrier)
    if (t + 1 < NT) {
      const size_t ko = (size_t)(t + 1) * 64;
      #pragma unroll
      for (int j = 0; j < 2; ++j) g2l16(A + srcA[j] + ko, (void*)(Ln + dstA[j]));
      #pragma unroll
      for (int j = 0; j < 3; ++j) g2l16(B + srcB[j] + ko, (void*)(Ln + dstB[j]));
    }

    __builtin_amdgcn_s_setprio(1);
    #pragma unroll
    for (int mi = 0; mi < 4; ++mi)
      #pragma unroll
      for (int ni = 0; ni < 3; ++ni)
        #pragma unroll
        for (int kk = 0; kk < 2; ++kk)
          acc[mi][ni] = __builtin_amdgcn_mfma_f32_16x16x32_bf16(a[mi][kk], b[ni][kk], acc[mi][ni], 0, 0, 0);
    __builtin_amdgcn_s_setprio(0);

    // boundary: next tile resident (drain hidden under the 24-MFMA phase)
    asm volatile("s_waitcnt vmcnt(0)" ::: "memory");
    __builtin_amdgcn_s_barrier();
  }

  // epilogue: bias + bf16 store (identical mapping to r11)
  #pragma unroll
  for (int ni = 0; ni < 3; ++ni) {
    const int col = n0 + wn*48 + ni*16 + c;
    const float bvl = bias[col];
    #pragma unroll
    for (int mi = 0; mi < 4; ++mi) {
      const int row0 = m0 + wm*64 + mi*16 + g*4;
      #pragma unroll
      for (int j = 0; j < 4; ++j)
        C[(size_t)(row0 + j)*N + col] = f2b(acc[mi][ni][j] + bvl);
    }
  }
}

// ---------------- 128x128 GEMM, BK=32, 4-buffer counted-vmcnt, f32 out (r9 proven) ----------------
__global__ __launch_bounds__(512, 1) void k_gemm128(const uint16_t* __restrict__ A,
                                                    const uint16_t* __restrict__ B,
                                                    const float* __restrict__ bias,
                                                    float* __restrict__ C,
                                                    int M, int N, int K){
  __shared__ uint16_t As[4*4096];   // [buf][rp(64)][slot8][8]
  __shared__ uint16_t Bs[4*4096];

  const int wg = blockIdx.x;
  const int xcd = wg & 7, bi = wg >> 3;
  const int m0 = (xcd*2 + (bi & 1)) * 128;     // XCD x: m-panels {2x, 2x+1}
  const int n0 = (bi >> 1) * 128;              // all 16 n-panels per XCD

  const int tid = threadIdx.x;
  const int wid = tid >> 6, l = tid & 63;
  const int wm = wid >> 2, wn = wid & 3;
  const int g = l >> 4, c = l & 15;

  const int rp_s = tid >> 3, q_s = tid & 7, s_s = q_s ^ (rp_s & 7);
  const int srcA = (m0 + rp_s*2 + (s_s >> 2)) * K + (s_s & 3) * 8;
  const int srcB = (n0 + rp_s*2 + (s_s >> 2)) * K + (s_s & 3) * 8;

  const int pg  = ((c & 1) << 2) | g;
  const int slb = (pg ^ ((c >> 1) & 7)) << 3;
  const int ra0 = wm*32 + (c >> 1);            // rows wm*64+c
  const int rb0 = wn*16 + (c >> 1);            // rows wn*32+c

  f32x4 acc[4][2] = {};
  const int NT = K >> 5;

  #pragma unroll
  for (int t0 = 0; t0 < 3; ++t0) {
    g2l16(A + srcA + t0*32, (void*)(As + t0*4096 + tid*8));
    g2l16(B + srcB + t0*32, (void*)(Bs + t0*4096 + tid*8));
  }
  asm volatile("s_waitcnt vmcnt(4)" ::: "memory");
  __builtin_amdgcn_s_barrier();

  #pragma unroll 4
  for (int t = 0; t < NT; ++t) {
    const uint16_t* __restrict__ Ab = As + (t & 3)*4096;
    const uint16_t* __restrict__ Bb = Bs + (t & 3)*4096;
    const int t3 = t + 3;
    const int b3 = (t3 & 3)*4096;

    short8 av[4], bv[2];
    #pragma unroll
    for (int mi = 0; mi < 4; ++mi)
      av[mi] = *(const short8*)&Ab[(ra0 + mi*8)*64 + slb];
    #pragma unroll
    for (int ni = 0; ni < 2; ++ni)
      bv[ni] = *(const short8*)&Bb[(rb0 + ni*8)*64 + slb];
    if (t3 < NT) {
      g2l16(A + srcA + t3*32, (void*)(As + b3 + tid*8));
      g2l16(B + srcB + t3*32, (void*)(Bs + b3 + tid*8));
    }
    __builtin_amdgcn_s_barrier();
    __builtin_amdgcn_s_setprio(1);
    #pragma unroll
    for (int mi = 0; mi < 4; ++mi)
      #pragma unroll
      for (int ni = 0; ni < 2; ++ni)
        acc[mi][ni] = __builtin_amdgcn_mfma_f32_16x16x32_bf16(av[mi], bv[ni], acc[mi][ni], 0, 0, 0);
    __builtin_amdgcn_s_setprio(0);
    asm volatile("s_waitcnt vmcnt(4)" ::: "memory");
    __builtin_amdgcn_s_barrier();
  }

  #pragma unroll
  for (int ni = 0; ni < 2; ++ni) {
    const int col = n0 + wn*32 + ni*16 + c;
    const float bvl = bias[col];
    #pragma unroll
    for (int mi = 0; mi < 4; ++mi) {
      const int row0 = m0 + wm*64 + mi*16 + g*4;
      #pragma unroll
      for (int j = 0; j < 4; ++j)
        C[(size_t)(row0 + j)*N + col] = acc[mi][ni][j] + bvl;
    }
  }
}

// ---------------- fused RoPE head-split (Q,K) + V transpose ----------------
__global__ __launch_bounds__(256) void k_rope_vt(const uint16_t* __restrict__ qkv,
                                                 const float* __restrict__ ct,
                                                 const float* __restrict__ st,
                                                 uint16_t* __restrict__ qo,
                                                 uint16_t* __restrict__ ko,
                                                 uint16_t* __restrict__ vt){
  const int blk = blockIdx.x, tid = threadIdx.x;
  if (blk < 4096) {
    int idx = blk * 256 + tid;   // which(2) x h(16) x s(2048) x db(16)
    int db = idx & 15;
    int s  = (idx >> 4) & 2047;
    int h  = (idx >> 15) & 15;
    int which = idx >> 19;
    const uint16_t* src = qkv + (size_t)s * QKV_N + which * 2048 + h * 128;
    uint16_t* dst = (which ? ko : qo) + (((size_t)(h*2048 + s)) << 7) + db*8;
    const float scale = which ? 1.0f : ATT_SCALE;
    int d0 = db * 8;
    union { short8 v; uint16_t u[8]; } o;
    if (d0 >= 64) {
      short8 xv = *(const short8*)(src + d0);
      #pragma unroll
      for (int e = 0; e < 8; ++e) o.u[e] = f2b(b2f((uint16_t)xv[e]) * scale);
    } else {
      int dd = d0 & 31;
      short8 a = *(const short8*)(src + dd);
      short8 b = *(const short8*)(src + dd + 32);
      float4 c0 = *(const float4*)(ct + s*32 + dd);
      float4 c1 = *(const float4*)(ct + s*32 + dd + 4);
      float4 s0 = *(const float4*)(st + s*32 + dd);
      float4 s1 = *(const float4*)(st + s*32 + dd + 4);
      float cc[8] = {c0.x,c0.y,c0.z,c0.w,c1.x,c1.y,c1.z,c1.w};
      float ss[8] = {s0.x,s0.y,s0.z,s0.w,s1.x,s1.y,s1.z,s1.w};
      #pragma unroll
      for (int e = 0; e < 8; ++e) {
        float x1 = b2f((uint16_t)a[e]), x2 = b2f((uint16_t)b[e]);
        float v = (d0 < 32) ? (x1*cc[e] - x2*ss[e]) : (x1*ss[e] + x2*cc[e]);
        o.u[e] = f2b(v * scale);
      }
    }
    *(short8*)dst = o.v;
  } else {
    __shared__ uint16_t tl[64][80];
    const int b = blk - 4096;               // h(16) x dt(2) x st(32)
    const int st_ = b & 31, dt = (b >> 5) & 1, h = b >> 6;
    const int s_l = tid >> 2, cch = (tid & 3) * 16;
    const uint16_t* src = qkv + (size_t)(st_*64 + s_l) * QKV_N + 4096 + h*128 + dt*64 + cch;
    short8 a = *(const short8*)src;
    short8 b2 = *(const short8*)(src + 8);
    #pragma unroll
    for (int e = 0; e < 8; ++e) {
      tl[cch + e][s_l]     = (uint16_t)a[e];
      tl[cch + 8 + e][s_l] = (uint16_t)b2[e];
    }
    __syncthreads();
    const int d_l = tid >> 2;
    uint16_t* dst = vt + ((size_t)h << 18) + (size_t)(dt*64 + d_l) * 2048 + st_*64 + cch;
    *(short8*)dst       = *(const short8*)&tl[d_l][cch];
    *(short8*)(dst + 8) = *(const short8*)&tl[d_l][cch + 8];
  }
}

// ---------------- causal flash attention v5 (r12 proven) ----------------
__global__ __launch_bounds__(512, 1) void k_attn(const uint16_t* __restrict__ Q,
                                                 const uint16_t* __restrict__ Kb,
                                                 const uint16_t* __restrict__ Vtg,
                                                 uint16_t* __restrict__ Out){
  __shared__ uint16_t Ks[2][2][64*128];   // [group][buf][k][d], swizzled
  __shared__ uint16_t Vs[2][2][128*64];   // [group][buf][d][k], swizzled
  __shared__ uint16_t Ps[8][16*88];       // per-wave P [q][k], stride 88

  const int bid = blockIdx.x;             // 256 blocks
  const int lin = (bid & 7) * 32 + (bid >> 3);
  const int h = lin >> 4;                 // XCD x gets heads {2x, 2x+1}
  const int pair = lin & 15;              // fold-pair within head

  const int tid = threadIdx.x, w = tid >> 6, l = tid & 63;
  const int gid = w >> 2, wq = w & 3;     // group, wave-in-group
  const int tg = tid & 255;               // thread index within group
  const int g = l >> 4, c = l & 15;
  const int swz = (c & 7) << 4;           // read-side byte swizzle

  const uint16_t* __restrict__ Qh = Q   + ((size_t)h << 18);
  const uint16_t* __restrict__ Kh = Kb  + ((size_t)h << 18);
  const uint16_t* __restrict__ Vh = Vtg + ((size_t)h << 18);
  float* scratch = (float*)&Ks[0][0][0];  // merge scratch (safe after last barrier)

  int koff[4], voff[4];
  #pragma unroll
  for (int j = 0; j < 4; ++j) {
    int kr = j*16 + (tg >> 4);                           // K row in tile
    koff[j] = kr*128 + (((tg & 15) ^ (kr & 7)) << 3);
    int vd = j*32 + (tg >> 3);                           // V^T row (d)
    voff[j] = vd*2048 + (((tg & 7) ^ (vd & 7)) << 3);
  }

  uint16_t* KsG = &Ks[gid][0][0];   // my group's K buffers (2 x 8192 elems)
  uint16_t* VsG = &Vs[gid][0][0];

  #pragma unroll 1
  for (int half = 0; half < 2; ++half) {
    const int qt = half ? (31 - pair) : pair;   // 64-row q-tile index
    const int nt = qt + 1;                      // KV tiles (KVBLK=64)
    const int nsteps = (nt + 1) >> 1;
    const int qrow = qt*64 + wq*16 + c;

    short8 qf[4];
    #pragma unroll
    for (int t = 0; t < 4; ++t)
      qf[t] = *(const short8*)&Qh[(size_t)qrow*128 + t*32 + g*8];

    f32x4 acc[8] = {};
    float mrow[4], lsum[4];
    #pragma unroll
    for (int j = 0; j < 4; ++j) { mrow[j] = -3e38f; lsum[j] = 0.0f; }

    if (gid < nt) {
      #pragma unroll
      for (int j = 0; j < 4; ++j) {
        g2l16(Kh + (size_t)gid*8192 + koff[j], (void*)(KsG + j*2048 + tg*8));
        g2l16(Vh + gid*64 + voff[j],           (void*)(VsG + j*2048 + tg*8));
      }
    }
    asm volatile("s_waitcnt vmcnt(0)" ::: "memory");
    __syncthreads();

    #pragma unroll 1
    for (int step = 0; step < nsteps; ++step) {
      const int kt = 2*step + gid;
      const int cur = step & 1;
      if (kt + 2 < nt) {
        const int k1 = kt + 2;
        #pragma unroll
        for (int j = 0; j < 4; ++j) {
          g2l16(Kh + (size_t)k1*8192 + koff[j], (void*)(KsG + (cur^1)*8192 + j*2048 + tg*8));
          g2l16(Vh + k1*64 + voff[j],           (void*)(VsG + (cur^1)*8192 + j*2048 + tg*8));
        }
      }

      if (kt < nt) {
        const int k0 = kt * 64;
        const uint16_t* Kcur = KsG + cur*8192;
        const uint16_t* Vcur = VsG + cur*8192;

        f32x4 sc4[4] = {};
        __builtin_amdgcn_s_setprio(1);
        #pragma unroll
        for (int ct2 = 0; ct2 < 4; ++ct2) {
          const char* krp = (const char*)Kcur + (ct2*16 + c)*256;
          #pragma unroll
          for (int t = 0; t < 4; ++t) {
            short8 kb = *(const short8*)(krp + ((t*64 + g*16) ^ swz));
            sc4[ct2] = __builtin_amdgcn_mfma_f32_16x16x32_bf16(qf[t], kb, sc4[ct2], 0, 0, 0);
          }
        }
        __builtin_amdgcn_s_setprio(0);

        // online softmax: defer-max fast path + per-lane partial l
        const bool lastt = (kt == nt - 1);
        float va[4][4];
        float m4[4];
        int fastok = 1;
        #pragma unroll
        for (int j = 0; j < 4; ++j) {
          const int qg = qt*64 + wq*16 + g*4 + j;
          float v0 = sc4[0][j], v1 = sc4[1][j], v2 = sc4[2][j], v3 = sc4[3][j];
          if (lastt) {
            if (k0 +      c > qg) v0 = -3e38f;
            if (k0 + 16 + c > qg) v1 = -3e38f;
            if (k0 + 32 + c > qg) v2 = -3e38f;
            if (k0 + 48 + c > qg) v3 = -3e38f;
          }
          va[j][0] = v0; va[j][1] = v1; va[j][2] = v2; va[j][3] = v3;
          float m = fmaxf(fmaxf(fmaxf(v0, v1), v2), v3);
          m4[j] = m;
          fastok &= (m <= mrow[j] + 8.0f) ? 1 : 0;
        }
        if (__all(fastok)) {
          #pragma unroll
          for (int j = 0; j < 4; ++j) {
            const float mj = mrow[j];
            const float p0 = __expf(va[j][0] - mj), p1 = __expf(va[j][1] - mj),
                        p2 = __expf(va[j][2] - mj), p3 = __expf(va[j][3] - mj);
            lsum[j] += (p0 + p1) + (p2 + p3);
            uint16_t* pw = &Ps[w][(g*4 + j)*88];
            pw[c] = f2b(p0); pw[16+c] = f2b(p1); pw[32+c] = f2b(p2); pw[48+c] = f2b(p3);
          }
        } else {
          #pragma unroll
          for (int j = 0; j < 4; ++j) {
            float t0 = m4[j];
            #pragma unroll
            for (int d2 = 1; d2 < 16; d2 <<= 1) t0 = fmaxf(t0, __shfl_xor(t0, d2, 64));
            const float mn = fmaxf(mrow[j], t0);
            const float scl = __expf(mrow[j] - mn);
            const float p0 = __expf(va[j][0] - mn), p1 = __expf(va[j][1] - mn),
                        p2 = __expf(va[j][2] - mn), p3 = __expf(va[j][3] - mn);
            lsum[j] = lsum[j]*scl + (p0 + p1) + (p2 + p3);
            mrow[j] = mn;
            #pragma unroll
            for (int n = 0; n < 8; ++n) acc[n][j] *= scl;
            uint16_t* pw = &Ps[w][(g*4 + j)*88];
            pw[c] = f2b(p0); pw[16+c] = f2b(p1); pw[32+c] = f2b(p2); pw[48+c] = f2b(p3);
          }
        }

        __builtin_amdgcn_s_setprio(1);
        #pragma unroll
        for (int kk = 0; kk < 2; ++kk) {
          short8 pf = *(const short8*)&Ps[w][c*88 + kk*32 + g*8];
          #pragma unroll
          for (int n = 0; n < 8; ++n) {
            const char* vrp = (const char*)Vcur + (n*16 + c)*128;
            short8 vf = *(const short8*)(vrp + ((kk*64 + g*16) ^ swz));
            acc[n] = __builtin_amdgcn_mfma_f32_16x16x32_bf16(pf, vf, acc[n], 0, 0, 0);
          }
        }
        __builtin_amdgcn_s_setprio(0);
      }

      asm volatile("s_waitcnt vmcnt(0)" ::: "memory");
      __syncthreads();
    }

    // reduce per-lane l partials -> per-row l (once per q-tile)
    float lrow[4];
    #pragma unroll
    for (int j = 0; j < 4; ++j) {
      float rs = lsum[j];
      #pragma unroll
      for (int d2 = 1; d2 < 16; d2 <<= 1) rs += __shfl_xor(rs, d2, 64);
      lrow[j] = rs;
    }

    // ---- merge group partial states: B (gid=1) publishes, A (gid=0) combines ----
    float* Up = scratch + wq * 2112;      // U[16][128] + m[16] + l[16]
    if (gid == 1) {
      #pragma unroll
      for (int j = 0; j < 4; ++j) {
        const int row = g*4 + j;
        #pragma unroll
        for (int n = 0; n < 8; ++n)
          Up[row*128 + n*16 + c] = acc[n][j];
        if (c == 0) { Up[2048 + row] = mrow[j]; Up[2064 + row] = lrow[j]; }
      }
    }
    __syncthreads();
    if (gid == 0) {
      #pragma unroll
      for (int j = 0; j < 4; ++j) {
        const int row = g*4 + j;
        const int qg = qt*64 + wq*16 + row;
        const float mB = Up[2048 + row], lB = Up[2064 + row];
        const float mn = fmaxf(mrow[j], mB);
        const float e1 = __expf(mrow[j] - mn);
        const float e2 = __expf(mB - mn);
        const float inv = 1.0f / (lrow[j]*e1 + lB*e2);
        #pragma unroll
        for (int n = 0; n < 8; ++n) {
          const float u = acc[n][j]*e1 + Up[row*128 + n*16 + c]*e2;
          Out[(size_t)qg*2048 + h*128 + n*16 + c] = f2b(u * inv);
        }
      }
    }
    __syncthreads();   // protect scratch before next half's staging overwrites K bufs
  }
}

extern "C" void kernel_launch(void* const* d_in, const int* in_sizes, int n_in,
                              void* d_out, int out_size, void* d_ws, size_t ws_size,
                              hipStream_t stream){
  const float* x    = (const float*)d_in[0];
  const float* Wqkv = (const float*)d_in[1];
  const float* bqkv = (const float*)d_in[2];
  const float* Wo   = (const float*)d_in[3];
  const float* bo   = (const float*)d_in[4];

  char* ws = (char*)d_ws;
  uint16_t* q_bf    = (uint16_t*)(ws);                 //  8.39 MB [16][2048][128]
  uint16_t* k_bf    = (uint16_t*)(ws + 8388608);       //  8.39 MB [16][2048][128]
  uint16_t* vt_bf   = (uint16_t*)(ws + 16777216);      //  8.39 MB [16][128][2048]
  uint16_t* attn_bf = (uint16_t*)(ws + 25165824);      //  8.39 MB (aliased with x_bf)
  uint16_t* x_bf    = attn_bf;                         //  x dead before attn writes
  uint16_t* wqkv_bf = (uint16_t*)(ws + 33554432);      // 25.17 MB
  uint16_t* wo_bf   = (uint16_t*)(ws + 58720256);      //  8.39 MB
  uint16_t* qkv_bf  = (uint16_t*)(ws + 67108864);      // 25.17 MB
  float*    cos_t   = (float*)(ws + 92274688);         //  0.26 MB
  float*    sin_t   = (float*)(ws + 92536832);         //  0.26 MB

  // fused converts + tables
  k_prep<<<dim3(10496), dim3(256), 0, stream>>>(x, Wqkv, Wo, x_bf, wqkv_bf, wo_bf,
                                                cos_t, sin_t);
  // qkv = x @ Wqkv^T + b   -> bf16 [2048][6144]  (BK=64, 1 barrier/tile, 512 blocks)
  k_gemmA<<<dim3(512), dim3(512), 0, stream>>>(x_bf, wqkv_bf, bqkv, qkv_bf);
  // RoPE + split Q,K (Q pre-scaled) + V transpose to [h][d][s]
  k_rope_vt<<<dim3(5120), dim3(256), 0, stream>>>(qkv_bf, cos_t, sin_t, q_bf, k_bf, vt_bf);
  // causal flash attention -> attn_bf [2048][2048]
  k_attn<<<dim3(256), dim3(512), 0, stream>>>(q_bf, k_bf, vt_bf, attn_bf);
  // out = attn @ Wo^T + bo -> f32 d_out (128^2 4-buffer pipeline, 256 blocks)
  k_gemm128<<<dim3(256), dim3(512), 0, stream>>>(attn_bf, wo_bf, bo, (float*)d_out,
                                                 2048, 2048, 2048);
}